// Round 11
// baseline (950.765 us; speedup 1.0000x reference)
//
#include <hip/hip_runtime.h>
#include <math.h>

#define N_NODES 100000
#define D 128
#define E_EDGES 600000
#define BN_EPS 1e-5f
#define RPS (N_NODES + 4)                 // padded rowptr stride per relation
#define N4V (N_NODES / 4)                 // 25000 int4 elements
#define SCAN_BLOCKS ((N4V + 255) / 256)   // 98

typedef __attribute__((ext_vector_type(8))) __bf16 bf16x8;
typedef __attribute__((ext_vector_type(4))) __bf16 bf16x4;
typedef __attribute__((ext_vector_type(16))) float f32x16;

// A-tile swizzle: full 4-bit XOR
__device__ __forceinline__ int qswz(int row, int q) { return q ^ (row & 15); }
// B-tile chunk swizzle
__device__ __forceinline__ int swz(int row, int c) { return c ^ ((row >> 1) & 3); }

// ---------------- degree histogram (all 3 relations, 4 edges/thread) ----------------
__global__ __launch_bounds__(256) void hist_kernel(
    const int* __restrict__ s0, const int* __restrict__ d0,
    const int* __restrict__ s1, const int* __restrict__ d1,
    const int* __restrict__ s2, const int* __restrict__ d2,
    int* __restrict__ outdeg, int* __restrict__ indeg)
{
    const int r = blockIdx.y;
    const int* src = (r == 0) ? s0 : ((r == 1) ? s1 : s2);
    const int* dst = (r == 0) ? d0 : ((r == 1) ? d1 : d2);
    int* od = outdeg + (size_t)r * N_NODES;
    int* id = indeg + (size_t)r * N_NODES;
    int i4 = blockIdx.x * 256 + threadIdx.x;
    if (i4 < E_EDGES / 4) {
        int4 s = ((const int4*)src)[i4];
        int4 d = ((const int4*)dst)[i4];
        atomicAdd(&od[s.x], 1); atomicAdd(&od[s.y], 1);
        atomicAdd(&od[s.z], 1); atomicAdd(&od[s.w], 1);
        atomicAdd(&id[d.x], 1); atomicAdd(&id[d.y], 1);
        atomicAdd(&id[d.z], 1); atomicAdd(&id[d.w], 1);
    }
}

// ---------------- parallel scan pass 1: per-block local exclusive scan ----------------
__global__ __launch_bounds__(256) void scan_part_kernel(
    const int* __restrict__ indeg, int* __restrict__ rowptr, int* __restrict__ bsum)
{
    const int r = blockIdx.y;
    const int t = threadIdx.x;
    const int lane = t & 63, wid = t >> 6;
    __shared__ int wsum[4], woff[4];
    int i4 = blockIdx.x * 256 + t;
    int4 v = (i4 < N4V) ? ((const int4*)(indeg + (size_t)r * N_NODES))[i4]
                        : make_int4(0, 0, 0, 0);
    int s0 = v.x, s1 = s0 + v.y, s2 = s1 + v.z, s3 = s2 + v.w;
    int x = s3;
    #pragma unroll
    for (int off = 1; off < 64; off <<= 1) {
        int y = __shfl_up(x, off);
        if (lane >= off) x += y;
    }
    if (lane == 63) wsum[wid] = x;
    __syncthreads();
    if (t < 4) { int s = 0; for (int j = 0; j < t; ++j) s += wsum[j]; woff[t] = s; }
    __syncthreads();
    int base = woff[wid] + (x - s3);
    if (i4 < N4V) {
        int idx = i4 * 4;
        int* rp = rowptr + (size_t)r * RPS;
        rp[idx] = base; rp[idx + 1] = base + s0; rp[idx + 2] = base + s1; rp[idx + 3] = base + s2;
    }
    if (t == 255) bsum[r * SCAN_BLOCKS + blockIdx.x] = woff[3] + wsum[3];
}

// ---------------- scan pass 2 ----------------
__global__ __launch_bounds__(256) void scan_mid_kernel(
    int* __restrict__ bsum, int* __restrict__ rowptr)
{
    const int t = threadIdx.x;
    const int lane = t & 63, wid = t >> 6;
    if (wid >= 3) return;
    const int r = wid;
    int carry = 0;
    for (int c = 0; c < (SCAN_BLOCKS + 63) / 64; ++c) {
        int idx = c * 64 + lane;
        int v = (idx < SCAN_BLOCKS) ? bsum[r * SCAN_BLOCKS + idx] : 0;
        int x = v;
        #pragma unroll
        for (int off = 1; off < 64; off <<= 1) {
            int y = __shfl_up(x, off);
            if (lane >= off) x += y;
        }
        if (idx < SCAN_BLOCKS) bsum[r * SCAN_BLOCKS + idx] = carry + x - v;
        carry += __shfl(x, 63);
    }
    if (lane == 0) rowptr[(size_t)r * RPS + N_NODES] = carry;
}

// ---------------- scan pass 3: add block offsets, cursor copy, AND norms (fused) ----------------
__global__ __launch_bounds__(256) void scan_add_kernel(
    int* __restrict__ rowptr, const int* __restrict__ bsum, int* __restrict__ cursor,
    const int* __restrict__ outdeg, const int* __restrict__ indeg,
    float* __restrict__ ns, float* __restrict__ nd)
{
    const int r = blockIdx.y;
    int i4 = blockIdx.x * 256 + threadIdx.x;
    if (i4 < N4V) {
        int off = bsum[r * SCAN_BLOCKS + blockIdx.x];
        int4* rp4 = (int4*)(rowptr + (size_t)r * RPS);
        int4 v = rp4[i4];
        v.x += off; v.y += off; v.z += off; v.w += off;
        rp4[i4] = v;
        ((int4*)(cursor + (size_t)r * N_NODES))[i4] = v;
        // fused norms
        int4 od = ((const int4*)(outdeg + (size_t)r * N_NODES))[i4];
        int4 id = ((const int4*)(indeg + (size_t)r * N_NODES))[i4];
        float4 nsv, ndv;
        nsv.x = rsqrtf((float)(od.x < 1 ? 1 : od.x));
        nsv.y = rsqrtf((float)(od.y < 1 ? 1 : od.y));
        nsv.z = rsqrtf((float)(od.z < 1 ? 1 : od.z));
        nsv.w = rsqrtf((float)(od.w < 1 ? 1 : od.w));
        ndv.x = rsqrtf((float)(id.x < 1 ? 1 : id.x));
        ndv.y = rsqrtf((float)(id.y < 1 ? 1 : id.y));
        ndv.z = rsqrtf((float)(id.z < 1 ? 1 : id.z));
        ndv.w = rsqrtf((float)(id.w < 1 ? 1 : id.w));
        ((float4*)(ns + (size_t)r * N_NODES))[i4] = nsv;
        ((float4*)(nd + (size_t)r * N_NODES))[i4] = ndv;
    }
}

// ---------------- CSR fill: edge record {src, ns[src]} ----------------
__global__ __launch_bounds__(256) void fill_kernel(
    const int* __restrict__ s0, const int* __restrict__ d0,
    const int* __restrict__ s1, const int* __restrict__ d1,
    const int* __restrict__ s2, const int* __restrict__ d2,
    const float* __restrict__ nsv,
    int* __restrict__ cursor, int2* __restrict__ eint)
{
    const int r = blockIdx.y;
    const int* src = (r == 0) ? s0 : ((r == 1) ? s1 : s2);
    const int* dst = (r == 0) ? d0 : ((r == 1) ? d1 : d2);
    int* cur = cursor + (size_t)r * N_NODES;
    int2* eg = eint + (size_t)r * E_EDGES;
    const float* ns_ = nsv + (size_t)r * N_NODES;
    int i = blockIdx.x * 256 + threadIdx.x;
    if (i < E_EDGES) {
        int s = src[i];
        int d = dst[i];
        int pos = atomicAdd(&cur[d], 1);
        eg[pos] = make_int2(s, __float_as_int(ns_[s]));
    }
}

// ---------------- W' precompute: grid (9, 8); block computes 16 k-rows x 128 cols ----------------
__global__ __launch_bounds__(256) void wprep_kernel(
    const float* __restrict__ Wrel, const float* __restrict__ Wfc,
    const float* __restrict__ gma, const float* __restrict__ rvar,
    __bf16* __restrict__ Whi, __bf16* __restrict__ Wlo)
{
    __shared__ float W2[128][132];
    __shared__ float W1p[16][132];
    const int b = blockIdx.x;   // l*3+r
    const int l = b / 3;
    const int by = blockIdx.y;  // k-row chunk
    const int t = threadIdx.x;

    const float* src1 = Wrel + (size_t)b * D * D;   // [k][j]
    const float* src2 = Wfc + (size_t)l * D * D;
    #pragma unroll
    for (int p = 0; p < 16; ++p) {
        int u = t + p * 256;
        int r = u >> 5, f = u & 31;
        *(float4*)&W2[r][f * 4] = *(const float4*)(src2 + r * D + f * 4);
    }
    #pragma unroll
    for (int p = 0; p < 2; ++p) {
        int u = t + p * 256;
        int r = u >> 5, f = u & 31;
        *(float4*)&W1p[r][f * 4] = *(const float4*)(src1 + (size_t)(by * 16 + r) * D + f * 4);
    }
    __syncthreads();

    const int rl = t >> 4;          // 0..15 local k-row
    const int cb = (t & 15) * 8;    // 8 cols
    float acc[8];
    #pragma unroll
    for (int j = 0; j < 8; ++j) acc[j] = 0.f;
    for (int k = 0; k < 128; ++k) {
        float a = W1p[rl][k];
        #pragma unroll
        for (int j = 0; j < 8; ++j) acc[j] = fmaf(a, W2[k][cb + j], acc[j]);
    }
    const int row = by * 16 + rl;
    #pragma unroll
    for (int j = 0; j < 8; ++j) {
        int colj = cb + j;
        float s = 1.0f;
        if (l < 2) s = gma[l * D + colj] * rsqrtf(rvar[l * D + colj] + BN_EPS);
        float v = acc[j] * s;
        __bf16 hb = (__bf16)v;
        __bf16 lb = (__bf16)(v - (float)hb);
        Whi[((size_t)b * D + colj) * D + row] = hb;
        Wlo[((size_t)b * D + colj) * D + row] = lb;
    }
}

// ---------------- bias precompute ----------------
__global__ __launch_bounds__(128) void bias_prep_kernel(
    const float* __restrict__ brel, const float* __restrict__ Wfc,
    const float* __restrict__ bfc,
    const float* __restrict__ gma, const float* __restrict__ bta,
    const float* __restrict__ rmean, const float* __restrict__ rvar,
    float* __restrict__ bvec)
{
    int j = threadIdx.x;
    int l = blockIdx.x;
    float acc = bfc[l * D + j];
    for (int k = 0; k < D; ++k) {
        float bs = brel[(l * 3 + 0) * D + k] + brel[(l * 3 + 1) * D + k] + brel[(l * 3 + 2) * D + k];
        acc = fmaf(bs, Wfc[((size_t)l * D + k) * D + j], acc);
    }
    if (l < 2) {
        float s = gma[l * D + j] * rsqrtf(rvar[l * D + j] + BN_EPS);
        acc = acc * s + (bta[l * D + j] - rmean[l * D + j] * s);
    }
    bvec[l * D + j] = acc;
}

// 16 FMAs of one edge's 4 float4 into accumulators A0_..A3_
#define FMA16T(W_, P_, Q_, R_, S_, A0_, A1_, A2_, A3_)                         \
    A0_.x = fmaf(W_, P_.x, A0_.x); A0_.y = fmaf(W_, P_.y, A0_.y);              \
    A0_.z = fmaf(W_, P_.z, A0_.z); A0_.w = fmaf(W_, P_.w, A0_.w);              \
    A1_.x = fmaf(W_, Q_.x, A1_.x); A1_.y = fmaf(W_, Q_.y, A1_.y);              \
    A1_.z = fmaf(W_, Q_.z, A1_.z); A1_.w = fmaf(W_, Q_.w, A1_.w);              \
    A2_.x = fmaf(W_, R_.x, A2_.x); A2_.y = fmaf(W_, R_.y, A2_.y);              \
    A2_.z = fmaf(W_, R_.z, A2_.z); A2_.w = fmaf(W_, R_.w, A2_.w);              \
    A3_.x = fmaf(W_, S_.x, A3_.x); A3_.y = fmaf(W_, S_.y, A3_.y);              \
    A3_.z = fmaf(W_, S_.z, A3_.z); A3_.w = fmaf(W_, S_.w, A3_.w);

// load one edge's 4 float4 (declares U0_..U3_)
#define LOADE(Q_, U0_, U1_, U2_, U3_)                                          \
    const float* pp_##U0_ = h + (size_t)Q_.x * D + gl * 4;                     \
    float4 U0_ = *(const float4*)(pp_##U0_);                                   \
    float4 U1_ = *(const float4*)(pp_##U0_ + 32);                              \
    float4 U2_ = *(const float4*)(pp_##U0_ + 64);                              \
    float4 U3_ = *(const float4*)(pp_##U0_ + 96);

// ---------------- fused layer: gather -> bf16 hi/lo LDS -> MFMA vs W' (3 relations) ----------------
// BM=128 rows/block, 512 threads = 8 waves; wave w: rows (w&3)*32..+31, cols (w>>2)*64..+63.
// LDS 80 KB -> 2 blocks/CU. Gather: 8-lane groups own 2 rows, processed INTERLEAVED
// (2 edges x 2 rows = 16 float4 sustained in flight across the whole row pair).
__global__ __launch_bounds__(512, 4) void fused_layer_kernel(
    const float* __restrict__ h,
    const int* __restrict__ rowptr,   // [3][RPS]
    const int2* __restrict__ eint,    // [3][E] {src, ns[src]}
    const float* __restrict__ ndv,    // [3][N]
    const __bf16* __restrict__ Whi,   // [3][col][k], this layer
    const __bf16* __restrict__ Wlo,
    float* __restrict__ out, const float* __restrict__ bias, int relu)
{
    __shared__ __bf16 Ah[128 * 128];   // 32 KB
    __shared__ __bf16 Al[128 * 128];   // 32 KB
    __shared__ __bf16 Bh[128 * 32];    // 8 KB
    __shared__ __bf16 Bl[128 * 32];    // 8 KB

    const int t = threadIdx.x;
    const int lane = t & 63;
    const int wid = t >> 6;           // 0..7
    const int wrow = wid & 3;         // 32-row quarter
    const int wcol = wid >> 2;        // 64-col half
    const int row0 = blockIdx.x * 128;
    const int g = t >> 3;             // 64 gather groups (2 rows each)
    const int gl = t & 7;             // lane in group: k-cols gl*4 + 32*j

    f32x16 acc[2];
    #pragma unroll
    for (int nt = 0; nt < 2; ++nt)
        #pragma unroll
        for (int i = 0; i < 16; ++i) acc[nt][i] = 0.0f;

    for (int r = 0; r < 3; ++r) {
        const int* rp = rowptr + (size_t)r * RPS;
        const int2* eg = eint + (size_t)r * E_EDGES;
        const float* nd_ = ndv + (size_t)r * N_NODES;

        // ---- gather: 2 rows interleaved, 2 edges per row per iteration ----
        const int rowlA = g * 2, rowlB = g * 2 + 1;
        const int growA = row0 + rowlA, growB = row0 + rowlB;
        float4 aA0 = {0,0,0,0}, aA1 = {0,0,0,0}, aA2 = {0,0,0,0}, aA3 = {0,0,0,0};
        float4 aB0 = {0,0,0,0}, aB1 = {0,0,0,0}, aB2 = {0,0,0,0}, aB3 = {0,0,0,0};
        int eA = 0, endA = 0, eB = 0, endB = 0;
        float scA = 0.f, scB = 0.f;
        if (growA < N_NODES) { eA = rp[growA]; endA = rp[growA + 1]; scA = nd_[growA]; }
        if (growB < N_NODES) { eB = rp[growB]; endB = rp[growB + 1]; scB = nd_[growB]; }

        // interleaved main loop: sustained 16 float4 in flight
        while (eA + 2 <= endA && eB + 2 <= endB) {
            int2 qA0 = eg[eA], qA1 = eg[eA + 1];
            int2 qB0 = eg[eB], qB1 = eg[eB + 1];
            LOADE(qA0, xA0, xA1, xA2, xA3);
            LOADE(qA1, yA0, yA1, yA2, yA3);
            LOADE(qB0, xB0, xB1, xB2, xB3);
            LOADE(qB1, yB0, yB1, yB2, yB3);
            float wA0 = __int_as_float(qA0.y), wA1 = __int_as_float(qA1.y);
            float wB0 = __int_as_float(qB0.y), wB1 = __int_as_float(qB1.y);
            FMA16T(wA0, xA0, xA1, xA2, xA3, aA0, aA1, aA2, aA3);
            FMA16T(wA1, yA0, yA1, yA2, yA3, aA0, aA1, aA2, aA3);
            FMA16T(wB0, xB0, xB1, xB2, xB3, aB0, aB1, aB2, aB3);
            FMA16T(wB1, yB0, yB1, yB2, yB3, aB0, aB1, aB2, aB3);
            eA += 2; eB += 2;
        }
        // drain row A
        for (; eA + 2 <= endA; eA += 2) {
            int2 qA0 = eg[eA], qA1 = eg[eA + 1];
            LOADE(qA0, xA0, xA1, xA2, xA3);
            LOADE(qA1, yA0, yA1, yA2, yA3);
            float wA0 = __int_as_float(qA0.y), wA1 = __int_as_float(qA1.y);
            FMA16T(wA0, xA0, xA1, xA2, xA3, aA0, aA1, aA2, aA3);
            FMA16T(wA1, yA0, yA1, yA2, yA3, aA0, aA1, aA2, aA3);
        }
        if (eA < endA) {
            int2 qA0 = eg[eA];
            LOADE(qA0, xA0, xA1, xA2, xA3);
            float wA0 = __int_as_float(qA0.y);
            FMA16T(wA0, xA0, xA1, xA2, xA3, aA0, aA1, aA2, aA3);
        }
        // drain row B
        for (; eB + 2 <= endB; eB += 2) {
            int2 qB0 = eg[eB], qB1 = eg[eB + 1];
            LOADE(qB0, xB0, xB1, xB2, xB3);
            LOADE(qB1, yB0, yB1, yB2, yB3);
            float wB0 = __int_as_float(qB0.y), wB1 = __int_as_float(qB1.y);
            FMA16T(wB0, xB0, xB1, xB2, xB3, aB0, aB1, aB2, aB3);
            FMA16T(wB1, yB0, yB1, yB2, yB3, aB0, aB1, aB2, aB3);
        }
        if (eB < endB) {
            int2 qB0 = eg[eB];
            LOADE(qB0, xB0, xB1, xB2, xB3);
            float wB0 = __int_as_float(qB0.y);
            FMA16T(wB0, xB0, xB1, xB2, xB3, aB0, aB1, aB2, aB3);
        }

        // scale + convert + LDS write (both rows)
        {
            aA0.x *= scA; aA0.y *= scA; aA0.z *= scA; aA0.w *= scA;
            aA1.x *= scA; aA1.y *= scA; aA1.z *= scA; aA1.w *= scA;
            aA2.x *= scA; aA2.y *= scA; aA2.z *= scA; aA2.w *= scA;
            aA3.x *= scA; aA3.y *= scA; aA3.z *= scA; aA3.w *= scA;
            aB0.x *= scB; aB0.y *= scB; aB0.z *= scB; aB0.w *= scB;
            aB1.x *= scB; aB1.y *= scB; aB1.z *= scB; aB1.w *= scB;
            aB2.x *= scB; aB2.y *= scB; aB2.z *= scB; aB2.w *= scB;
            aB3.x *= scB; aB3.y *= scB; aB3.z *= scB; aB3.w *= scB;
            float4 avA[4] = {aA0, aA1, aA2, aA3};
            float4 avB[4] = {aB0, aB1, aB2, aB3};
            #pragma unroll
            for (int j = 0; j < 4; ++j) {
                int q = (gl >> 1) + 4 * j;
                int idxA = rowlA * 128 + qswz(rowlA, q) * 8 + (gl & 1) * 4;
                int idxB = rowlB * 128 + qswz(rowlB, q) * 8 + (gl & 1) * 4;
                bf16x4 hvA, lvA, hvB, lvB;
                float* apA = &avA[j].x;
                float* apB = &avB[j].x;
                #pragma unroll
                for (int c = 0; c < 4; ++c) {
                    __bf16 hbA = (__bf16)apA[c];
                    hvA[c] = hbA;
                    lvA[c] = (__bf16)(apA[c] - (float)hbA);
                    __bf16 hbB = (__bf16)apB[c];
                    hvB[c] = hbB;
                    lvB[c] = (__bf16)(apB[c] - (float)hbB);
                }
                *(bf16x4*)&Ah[idxA] = hvA;
                *(bf16x4*)&Al[idxA] = lvA;
                *(bf16x4*)&Ah[idxB] = hvB;
                *(bf16x4*)&Al[idxB] = lvB;
            }
        }

        // ---- MFMA over 4 K-slices ----
        for (int ks = 0; ks < 4; ++ks) {
            // stage B slice: 128 cols x 32 k (hi+lo per thread)
            {
                int colj = t >> 2;
                int c = t & 3;
                int idx = colj * 32 + swz(colj, c) * 8;
                const __bf16* sh = Whi + (size_t)r * D * D + (size_t)colj * D + ks * 32 + c * 8;
                const __bf16* sl = Wlo + (size_t)r * D * D + (size_t)colj * D + ks * 32 + c * 8;
                *(bf16x8*)&Bh[idx] = *(const bf16x8*)sh;
                *(bf16x8*)&Bl[idx] = *(const bf16x8*)sl;
            }
            __syncthreads();   // A-writes (ks==0) and B-writes visible

            const int arow = lane & 31;
            const int kgrp = lane >> 5;
            #pragma unroll
            for (int ksub = 0; ksub < 2; ++ksub) {
                int ac = ksub * 2 + kgrp;
                int arow_g = wrow * 32 + arow;
                int aidx = arow_g * 128 + qswz(arow_g, ks * 4 + ac) * 8;
                bf16x8 ahv = *(const bf16x8*)&Ah[aidx];
                bf16x8 alv = *(const bf16x8*)&Al[aidx];
                #pragma unroll
                for (int nt = 0; nt < 2; ++nt) {
                    int colg = wcol * 64 + nt * 32 + arow;
                    int bidx = colg * 32 + swz(colg, ac) * 8;
                    bf16x8 bhv = *(const bf16x8*)&Bh[bidx];
                    bf16x8 blv = *(const bf16x8*)&Bl[bidx];
                    acc[nt] = __builtin_amdgcn_mfma_f32_32x32x16_bf16(ahv, bhv, acc[nt], 0, 0, 0);
                    acc[nt] = __builtin_amdgcn_mfma_f32_32x32x16_bf16(ahv, blv, acc[nt], 0, 0, 0);
                    acc[nt] = __builtin_amdgcn_mfma_f32_32x32x16_bf16(alv, bhv, acc[nt], 0, 0, 0);
                }
            }
            __syncthreads();   // MFMA reads done before next stage/gather writes
        }
    }

    // ---- epilogue: bias (+ ReLU), single write ----
    const int colb = lane & 31;
    const int rq = lane >> 5;
    #pragma unroll
    for (int nt = 0; nt < 2; ++nt) {
        int colg = wcol * 64 + nt * 32 + colb;
        float bv = bias[colg];
        #pragma unroll
        for (int reg = 0; reg < 16; ++reg) {
            int rowl = wrow * 32 + (reg & 3) + 8 * (reg >> 2) + 4 * rq;
            int grow = row0 + rowl;
            if (grow < N_NODES) {
                float z = acc[nt][reg] + bv;
                if (relu) z = fmaxf(z, 0.f);
                out[(size_t)grow * D + colg] = z;
            }
        }
    }
}

// ---------------- launch ----------------
extern "C" void kernel_launch(void* const* d_in, const int* in_sizes, int n_in,
                              void* d_out, int out_size, void* d_ws, size_t ws_size,
                              hipStream_t stream)
{
    const float* x      = (const float*)d_in[0];
    const int* seq_src  = (const int*)d_in[1];
    const int* seq_dst  = (const int*)d_in[2];
    const int* knn_src  = (const int*)d_in[3];
    const int* knn_dst  = (const int*)d_in[4];
    const int* dis_src  = (const int*)d_in[5];
    const int* dis_dst  = (const int*)d_in[6];
    const float* Wrel   = (const float*)d_in[7];   // [3][3][128][128]
    const float* brel   = (const float*)d_in[8];   // [3][3][128]
    const float* Wfc    = (const float*)d_in[9];   // [3][128][128]
    const float* bfc    = (const float*)d_in[10];  // [3][128]
    const float* gma    = (const float*)d_in[11];  // [2][128]
    const float* bta    = (const float*)d_in[12];
    const float* rmean  = (const float*)d_in[13];
    const float* rvar   = (const float*)d_in[14];
    float* out = (float*)d_out;

    const size_t ND = (size_t)N_NODES * D;
    float* ws   = (float*)d_ws;
    float* h0   = ws;                         // N*D
    float* h1   = h0 + ND;                    // N*D
    float* ns_  = h1 + ND;                    // 3*N
    float* nd_  = ns_ + 3 * N_NODES;          // 3*N
    float* bvec = nd_ + 3 * N_NODES;          // 3*128
    __bf16* Whi = (__bf16*)(bvec + 3 * D);    // 9*128*128
    __bf16* Wlo = Whi + (size_t)9 * D * D;
    int* outdeg = (int*)(Wlo + (size_t)9 * D * D);   // 3*N
    int* indeg  = outdeg + 3 * N_NODES;               // 3*N
    int* rowptr = indeg + 3 * N_NODES;                // 3*RPS
    int* cursor = rowptr + 3 * RPS;                   // 3*N
    int* bsum   = cursor + 3 * N_NODES;               // 3*SCAN_BLOCKS
    int2* eint  = (int2*)(bsum + 3 * SCAN_BLOCKS + 2); // 3*E {src, w} (8B aligned)

    // ---- graph preprocessing ----
    hipMemsetAsync(outdeg, 0, (size_t)6 * N_NODES * sizeof(int), stream);
    hist_kernel<<<dim3((E_EDGES / 4 + 255) / 256, 3), 256, 0, stream>>>(
        seq_src, seq_dst, knn_src, knn_dst, dis_src, dis_dst, outdeg, indeg);
    scan_part_kernel<<<dim3(SCAN_BLOCKS, 3), 256, 0, stream>>>(indeg, rowptr, bsum);
    scan_mid_kernel<<<1, 256, 0, stream>>>(bsum, rowptr);
    scan_add_kernel<<<dim3(SCAN_BLOCKS, 3), 256, 0, stream>>>(
        rowptr, bsum, cursor, outdeg, indeg, ns_, nd_);
    fill_kernel<<<dim3((E_EDGES + 255) / 256, 3), 256, 0, stream>>>(
        seq_src, seq_dst, knn_src, knn_dst, dis_src, dis_dst, ns_, cursor, eint);

    // ---- weight/bias precompute ----
    wprep_kernel<<<dim3(9, 8), 256, 0, stream>>>(Wrel, Wfc, gma, rvar, Whi, Wlo);
    bias_prep_kernel<<<3, 128, 0, stream>>>(brel, Wfc, bfc, gma, bta, rmean, rvar, bvec);

    // ---- layers (fully fused) ----
    const int GB = (N_NODES + 127) / 128;   // 782
    fused_layer_kernel<<<GB, 512, 0, stream>>>(
        x, rowptr, eint, nd_, Whi, Wlo, h0, bvec, 1);
    fused_layer_kernel<<<GB, 512, 0, stream>>>(
        h0, rowptr, eint, nd_, Whi + (size_t)3 * D * D, Wlo + (size_t)3 * D * D,
        h1, bvec + D, 1);
    fused_layer_kernel<<<GB, 512, 0, stream>>>(
        h1, rowptr, eint, nd_, Whi + (size_t)6 * D * D, Wlo + (size_t)6 * D * D,
        out, bvec + 2 * D, 0);
}